// Round 7
// baseline (348.717 us; speedup 1.0000x reference)
//
#include <hip/hip_runtime.h>

// ---------------------------------------------------------------------------
// GraphConv x3 + FC on MI355X — R13: gemm_u with B in LDS (matid-per-block).
// Identity: (A x0)K1 + (A^2 x0)K2 + (A^3 x0)K3 = A(u1 + A(u2 + A u3)),
// u_m = x0 K_m (N x 64). 64-dim propagation (128B gather rows).
// R13: registers can't hold B without killing occupancy (R11: 2 waves/SIMD;
// R12: spills, +55MB scratch traffic). So: each block owns one matid and
// stages its 16 KB B-panel in LDS; waves re-read b-frags per tile via
// conflict-free ds_read_b128. launch_bounds(256,6) -> ~85 regs, 6 waves/SIMD.
// ---------------------------------------------------------------------------

typedef short bf16x8 __attribute__((ext_vector_type(8)));
typedef float f32x4 __attribute__((ext_vector_type(4)));

#define CAPB 8192   // bucket capacity (mean 4082, sigma ~64 -> 64 sigma slack)

__device__ inline float bf2f(unsigned short u) {
    union { unsigned int i; float f; } v; v.i = ((unsigned int)u) << 16; return v.f;
}
__device__ inline unsigned short f2bf(float f) {
    union { float f; unsigned int i; } v; v.f = f;
    unsigned int r = v.i + 0x7FFFu + ((v.i >> 16) & 1u);   // RNE
    return (unsigned short)(r >> 16);
}

// ---- prep: stage1 mats [0,64) | edge partition [64,64+NA) ------------------
__global__ __launch_bounds__(512) void prep_kernel(
    const float* __restrict__ Wr2, const float* __restrict__ Wo2,
    const float* __restrict__ fcw, float* __restrict__ K0_2, float* __restrict__ K1_2,
    const int* __restrict__ src, const int* __restrict__ dst,
    int* __restrict__ gcur, unsigned int* __restrict__ bucketed, int e, int NA, int NB) {
    int b = blockIdx.x, t = threadIdx.x;
    if (b < 64) {
        if (t < 256) {
            int matid = b >> 5;
            const float* W = matid ? Wr2 : Wo2;
            float* K = matid ? K1_2 : K0_2;
            int i = t & 127;
            int j = (b & 31) * 2 + (t >> 7);
            float acc = 0.f;
            for (int k = 0; k < 128; k++) acc += W[k * 128 + i] * fcw[j * 128 + k];
            K[i * 64 + j] = acc;
        }
        return;
    }
    b -= 64;
    if (b < NA) {
        __shared__ int sHist[512], sScan[512], sExcl[512], sGbase[512];
        __shared__ unsigned int lbuf[2048];
        __shared__ unsigned short lbkt[2048];
        int e0 = b * 2048;
        int cnt = e - e0; if (cnt > 2048) cnt = 2048;
        sHist[t] = 0;
        __syncthreads();
        unsigned int pk[4]; int bk[4];
#pragma unroll
        for (int k = 0; k < 4; k++) {
            int j = t + k * 512;
            if (j < cnt) {
                int d = dst[e0 + j], s = src[e0 + j];
                bk[k] = d >> 8;
                pk[k] = ((unsigned int)s << 8) | (unsigned int)(d & 255);
                atomicAdd(&sHist[bk[k]], 1);
            } else bk[k] = -1;
        }
        __syncthreads();
        int h = sHist[t];
        if (t < NB && h > 0) sGbase[t] = atomicAdd(&gcur[t], h);
        else sGbase[t] = 0;
        int xv = h; sScan[t] = xv; __syncthreads();
        for (int o = 1; o < 512; o <<= 1) {
            int y = (t >= o) ? sScan[t - o] : 0;
            __syncthreads();
            xv += y; sScan[t] = xv;
            __syncthreads();
        }
        sExcl[t] = xv - h;      // block-local exclusive offsets per bucket
        sHist[t] = 0;           // becomes local cursor
        __syncthreads();
#pragma unroll
        for (int k = 0; k < 4; k++) {
            if (bk[k] >= 0) {
                int r = atomicAdd(&sHist[bk[k]], 1);
                int pos = sExcl[bk[k]] + r;
                lbuf[pos] = pk[k];
                lbkt[pos] = (unsigned short)bk[k];
            }
        }
        __syncthreads();
        for (int j = t; j < cnt; j += 512) {
            int b2 = lbkt[j];
            int idx = sGbase[b2] + (j - sExcl[b2]);
            if (idx < CAPB) bucketed[(size_t)b2 * CAPB + idx] = lbuf[j];
        }
    }
}

// ---- pass B: per-bucket deg/start/csr --------------------------------------
__global__ __launch_bounds__(256) void partB_kernel(
    const unsigned int* __restrict__ bucketed, const int* __restrict__ gcur,
    int* __restrict__ deg, int* __restrict__ start, int* __restrict__ csr, int n) {
    int b = blockIdx.x, t = threadIdx.x;
    __shared__ int ldeg[256], lscan[256], red[256];
    __shared__ int csr_base_s;
    int cnt = gcur[b]; if (cnt > CAPB) cnt = CAPB;
    // csr base = sum of counts of buckets < b
    int part = 0;
    for (int q = t; q < b; q += 256) { int c = gcur[q]; part += (c > CAPB ? CAPB : c); }
    red[t] = part; __syncthreads();
    for (int o = 128; o > 0; o >>= 1) { if (t < o) red[t] += red[t + o]; __syncthreads(); }
    if (t == 0) csr_base_s = red[0];
    ldeg[t] = 0;
    __syncthreads();
    const unsigned int* bd = bucketed + (size_t)b * CAPB;
    for (int j = t; j < cnt; j += 256) atomicAdd(&ldeg[bd[j] & 255], 1);
    __syncthreads();
    int h = ldeg[t];
    int xv = h; lscan[t] = xv; __syncthreads();
    for (int o = 1; o < 256; o <<= 1) {
        int y = (t >= o) ? lscan[t - o] : 0;
        __syncthreads();
        xv += y; lscan[t] = xv;
        __syncthreads();
    }
    int excl = xv - h;
    int csr_base = csr_base_s;
    int node = b * 256 + t;
    if (node < n) { deg[node] = h; start[node] = csr_base + excl; }
    __syncthreads();
    lscan[t] = excl;    // per-local-node exclusive offset
    ldeg[t] = 0;        // cursor
    __syncthreads();
    for (int j = t; j < cnt; j += 256) {
        unsigned int pkd = bd[j];
        int d = pkd & 255;
        int r = atomicAdd(&ldeg[d], 1);
        csr[csr_base + lscan[d] + r] = (int)(pkd >> 8);
    }
}

// ---- stage2: K*_1 from layer-1 (0-based) weights ---------------------------
__global__ __launch_bounds__(256) void stage2_kernel(
    const float* __restrict__ Wr1, const float* __restrict__ Wo1,
    const float* __restrict__ K0_2, const float* __restrict__ K1_2,
    float* __restrict__ K0_1, float* __restrict__ K1_1, float* __restrict__ K2_1) {
    int b = blockIdx.x, t = threadIdx.x;
    int matid = b >> 5;
    int i = t & 127;
    int j = (b & 31) * 2 + (t >> 7);
    float acc = 0.f;
    if (matid == 0) {
        for (int k = 0; k < 128; k++) acc += Wo1[k * 128 + i] * K0_2[k * 64 + j];
        K0_1[i * 64 + j] = acc;
    } else if (matid == 1) {
        for (int k = 0; k < 128; k++)
            acc += Wr1[k * 128 + i] * K0_2[k * 64 + j] + Wo1[k * 128 + i] * K1_2[k * 64 + j];
        K1_1[i * 64 + j] = acc;
    } else {
        for (int k = 0; k < 128; k++) acc += Wr1[k * 128 + i] * K1_2[k * 64 + j];
        K2_1[i * 64 + j] = acc;
    }
}

// ---- stage3: final K0..K3 packed bf16 (permuted slots) + bias vectors ------
// Nw slot p = ((c&3)<<4)|(c>>2) holds logical output column c, so gemm_u's
// tile t / lane m (reading slot t*16+m) emits logical column 4m+t.
__global__ __launch_bounds__(256) void stage3_kernel(
    const float* __restrict__ Wr0, const float* __restrict__ Wo0,
    const float* __restrict__ K0_1, const float* __restrict__ K1_1, const float* __restrict__ K2_1,
    const float* __restrict__ K0_2, const float* __restrict__ K1_2,
    const float* __restrict__ br, const float* __restrict__ fcw, const float* __restrict__ fcb,
    unsigned short* __restrict__ Nw, float* __restrict__ Bv) {
    int b = blockIdx.x, t = threadIdx.x;
    if (b < 128) {
        int matid = b >> 5;
        int i = t & 127;
        int o = (b & 31) * 2 + (t >> 7);
        float acc = 0.f;
        if (matid == 0) {
            for (int k = 0; k < 128; k++) acc += Wo0[k * 128 + i] * K0_1[k * 64 + o];
        } else if (matid == 1) {
            for (int k = 0; k < 128; k++)
                acc += Wr0[k * 128 + i] * K0_1[k * 64 + o] + Wo0[k * 128 + i] * K1_1[k * 64 + o];
        } else if (matid == 2) {
            for (int k = 0; k < 128; k++)
                acc += Wr0[k * 128 + i] * K1_1[k * 64 + o] + Wo0[k * 128 + i] * K2_1[k * 64 + o];
        } else {
            for (int k = 0; k < 128; k++) acc += Wr0[k * 128 + i] * K2_1[k * 64 + o];
        }
        int p = ((o & 3) << 4) | (o >> 2);
        Nw[p * 512 + matid * 128 + i] = f2bf(acc);
        return;
    }
    const float* br0 = br;
    const float* br1 = br + 128;
    const float* br2 = br + 256;
    int j = t & 63;
    int which = t >> 6;
    if (which == 0) {
        float acc = fcb[j];
        for (int k = 0; k < 128; k++) acc += br2[k] * fcw[j * 128 + k];
        for (int k = 0; k < 128; k++) acc += br1[k] * K0_2[k * 64 + j];
        for (int k = 0; k < 128; k++) acc += br0[k] * K0_1[k * 64 + j];
        Bv[j] = acc;                       // B0
    } else if (which == 1) {
        float acc = 0.f;
        for (int k = 0; k < 128; k++) acc += br1[k] * K1_2[k * 64 + j];
        for (int k = 0; k < 128; k++) acc += br0[k] * K1_1[k * 64 + j];
        Bv[64 + j] = acc;                  // B1
    } else if (which == 2) {
        float acc = 0.f;
        for (int k = 0; k < 128; k++) acc += br0[k] * K2_1[k * 64 + j];
        Bv[128 + j] = acc;                 // B2
    }
}

// ---- gemm_u: U[m][n][64] = bf16(x0 @ K_m), m=0..3, MFMA ---------------------
// matid = blockIdx & 3 (consecutive blocks share x rows -> L2 dedup).
// Block stages its 16 KB B-panel to LDS once; 4 waves x 2 row-tiles each.
// LDS layout [(kk*4+quad)*64 + slot]*8 bf16 -> per-quad contiguous 256B
// ds_read_b128 (2-way bank alias = free).
__global__ __launch_bounds__(256, 6) void gemm_u_kernel(
    const float* __restrict__ x, const unsigned short* __restrict__ Nw,
    unsigned short* __restrict__ U, int n) {
    __shared__ unsigned short Blds[8192];   // 16 KB
    int matid = blockIdx.x & 3;
    int blk   = blockIdx.x >> 2;
    int tid   = threadIdx.x;

    // stage B[matid]: 1024 x 16B groups, contiguous LDS writes
    {
        const uint4* nw4 = (const uint4*)Nw;   // Nw: 64 slots x 512 elems = 64 x 64 uint4
        uint4* lds4 = (uint4*)Blds;
        for (int g = tid; g < 1024; g += 256) {
            int slot = g & 63;
            int kq   = g >> 6;                 // kk*4+quad
            lds4[g] = nw4[(size_t)slot * 64 + matid * 16 + kq];
        }
    }
    __syncthreads();

    int wave = tid >> 6;
    int lane = tid & 63;
    int m    = lane & 15;
    int quad = lane >> 4;
    size_t n64 = (size_t)n * 64;
    unsigned short* up = U + (size_t)matid * n64;

#pragma unroll
    for (int w = 0; w < 2; w++) {
        int row0 = (blk * 8 + wave * 2 + w) * 16;
        if (row0 >= n) break;

        // load + convert this tile's x rows (row-clamped)
        int arow = row0 + m; if (arow >= n) arow = n - 1;
        const float* xr = x + (size_t)arow * 128 + quad * 8;
        bf16x8 a[4];
#pragma unroll
        for (int kk = 0; kk < 4; kk++) {
            float4 v0 = *(const float4*)(xr + kk * 32);
            float4 v1 = *(const float4*)(xr + kk * 32 + 4);
            a[kk][0] = (short)f2bf(v0.x); a[kk][1] = (short)f2bf(v0.y);
            a[kk][2] = (short)f2bf(v0.z); a[kk][3] = (short)f2bf(v0.w);
            a[kk][4] = (short)f2bf(v1.x); a[kk][5] = (short)f2bf(v1.y);
            a[kk][6] = (short)f2bf(v1.z); a[kk][7] = (short)f2bf(v1.w);
        }

        f32x4 acc[4];
#pragma unroll
        for (int t = 0; t < 4; t++) acc[t] = (f32x4){0.f, 0.f, 0.f, 0.f};
#pragma unroll
        for (int kk = 0; kk < 4; kk++) {
            bf16x8 bq[4];
#pragma unroll
            for (int t = 0; t < 4; t++)
                bq[t] = *(const bf16x8*)(Blds + ((kk * 4 + quad) * 64 + t * 16 + m) * 8);
#pragma unroll
            for (int t = 0; t < 4; t++)
                acc[t] = __builtin_amdgcn_mfma_f32_16x16x32_bf16(a[kk], bq[t], acc[t], 0, 0, 0);
        }

#pragma unroll
        for (int r = 0; r < 4; r++) {
            int orow = row0 + quad * 4 + r;
            if (orow < n) {
                ushort4 o4;
                o4.x = f2bf(acc[0][r]); o4.y = f2bf(acc[1][r]);
                o4.z = f2bf(acc[2][r]); o4.w = f2bf(acc[3][r]);
                *(ushort4*)(up + (size_t)orow * 64 + m * 4) = o4;
            }
        }
    }
}

// ---- agg64: 8 nodes per wave, one 8-lane group per node, shuffle-free ------
// MODE 0: outb = A*in + addv, d2 = A*deg fused
// MODE 1: outb = A*in + addv
// MODE 2: outf = A*in + addv + B0 + deg*B1 + d2*B2   (final f32 output)
template <int MODE>
__global__ __launch_bounds__(256) void agg64_kernel(
    const unsigned short* __restrict__ in, const unsigned short* __restrict__ addv,
    const int* __restrict__ csr, const int* __restrict__ start, const int* __restrict__ deg,
    unsigned short* __restrict__ outb, float* __restrict__ outf,
    const float* __restrict__ Bv, int* __restrict__ d2w, const int* __restrict__ d2r, int n) {
    int tid = threadIdx.x;
    int fl  = tid & 7;                       // lane within 8-lane group
    int node = blockIdx.x * 32 + (tid >> 3); // one node per group
    if (node >= n) return;

    // hoist bias columns (node-independent) for MODE 2
    float b0[8], b1[8], b2[8];
    if (MODE == 2) {
#pragma unroll
        for (int j = 0; j < 8; j++) {
            int o = fl * 8 + j;
            b0[j] = Bv[o]; b1[j] = Bv[64 + o]; b2[j] = Bv[128 + o];
        }
    }

    int s0 = start[node];
    int d  = deg[node];

    float acc[8];
#pragma unroll
    for (int j = 0; j < 8; j++) acc[j] = 0.f;
    int dsum = 0;

#pragma unroll 4
    for (int i = 0; i < d; i++) {
        int s = csr[s0 + i];
        bf16x8 v = *(const bf16x8*)(in + (size_t)s * 64 + fl * 8);
#pragma unroll
        for (int j = 0; j < 8; j++) acc[j] += bf2f((unsigned short)v[j]);
        if (MODE == 0 && fl == 0) dsum += deg[s];
    }
    if (MODE == 0 && fl == 0) d2w[node] = dsum;

    bf16x8 av = *(const bf16x8*)(addv + (size_t)node * 64 + fl * 8);
    if (MODE < 2) {
        bf16x8 o;
#pragma unroll
        for (int j = 0; j < 8; j++) o[j] = (short)f2bf(acc[j] + bf2f((unsigned short)av[j]));
        *(bf16x8*)(outb + (size_t)node * 64 + fl * 8) = o;
    } else {
        float dg = (float)d;
        float dd = (float)d2r[node];
        float ov[8];
#pragma unroll
        for (int j = 0; j < 8; j++)
            ov[j] = acc[j] + bf2f((unsigned short)av[j]) + b0[j] + dg * b1[j] + dd * b2[j];
        float* op = outf + (size_t)node * 64 + fl * 8;
        *(float4*)(op)     = make_float4(ov[0], ov[1], ov[2], ov[3]);
        *(float4*)(op + 4) = make_float4(ov[4], ov[5], ov[6], ov[7]);
    }
}

// ---------------------------------------------------------------------------
extern "C" void kernel_launch(void* const* d_in, const int* in_sizes, int n_in,
                              void* d_out, int out_size, void* d_ws, size_t ws_size,
                              hipStream_t stream) {
    const float* x      = (const float*)d_in[0];
    const int*   ei     = (const int*)d_in[1];
    const float* W_rel  = (const float*)d_in[2];
    const float* b_rel  = (const float*)d_in[3];
    const float* W_root = (const float*)d_in[4];
    const float* fc_w   = (const float*)d_in[5];
    const float* fc_b   = (const float*)d_in[6];

    const int n = in_sizes[0] / 128;      // 100000
    const int e = in_sizes[1] / 2;        // 1600000
    const int* src = ei;
    const int* dst = ei + e;

    const int NB  = (n + 255) >> 8;       // 391 buckets of 256 nodes
    const int NA  = (e + 2047) / 2048;    // 782 partition blocks
    const int NT  = (n + 15) / 16;        // MFMA row-tiles
    const int NGB = (NT + 7) / 8;         // row-blocks (8 tiles each)

    char* p = (char*)d_ws;
    auto take = [&](size_t bytes) -> void* {
        void* r = (void*)p;
        p += (bytes + 255) & ~(size_t)255;
        return r;
    };
    unsigned short* U  = (unsigned short*)take((size_t)n * 256 * 2);  // u0..u3
    unsigned short* w1 = (unsigned short*)take((size_t)n * 64 * 2);
    unsigned short* w2 = (unsigned short*)take((size_t)n * 64 * 2);
    int* deg    = (int*)take((size_t)n * 4);
    int* start  = (int*)take((size_t)n * 4);
    int* d2     = (int*)take((size_t)n * 4);
    int* csr    = (int*)take((size_t)e * 4);
    unsigned int* bucketed = (unsigned int*)take((size_t)NB * CAPB * 4);
    int* gcur   = (int*)take((size_t)NB * 4);
    float* K0_2 = (float*)take(128 * 64 * 4);
    float* K1_2 = (float*)take(128 * 64 * 4);
    float* K0_1 = (float*)take(128 * 64 * 4);
    float* K1_1 = (float*)take(128 * 64 * 4);
    float* K2_1 = (float*)take(128 * 64 * 4);
    unsigned short* Nw = (unsigned short*)take(64 * 512 * 2);
    float* Bv   = (float*)take(192 * 4);

    size_t n64 = (size_t)n * 64;
    unsigned short* u0 = U;
    unsigned short* u1 = U + n64;
    unsigned short* u2 = U + 2 * n64;
    unsigned short* u3 = U + 3 * n64;

    hipMemsetAsync(gcur, 0, (size_t)NB * 4, stream);
    prep_kernel<<<64 + NA, 512, 0, stream>>>(
        W_rel + 2 * 16384, W_root + 2 * 16384, fc_w, K0_2, K1_2,
        src, dst, gcur, bucketed, e, NA, NB);
    partB_kernel<<<NB, 256, 0, stream>>>(bucketed, gcur, deg, start, csr, n);
    stage2_kernel<<<96, 256, 0, stream>>>(
        W_rel + 16384, W_root + 16384, K0_2, K1_2, K0_1, K1_1, K2_1);
    stage3_kernel<<<129, 256, 0, stream>>>(
        W_rel, W_root, K0_1, K1_1, K2_1, K0_2, K1_2, b_rel, fc_w, fc_b, Nw, Bv);

    gemm_u_kernel<<<NGB * 4, 256, 0, stream>>>(x, Nw, U, n);

    const int AGB = (n + 31) / 32;        // 32 nodes per 256-thread block
    // w1 = A u3 + u2 ; w2 = A w1 + u1 ; out = A w2 + u0 + B0 + deg B1 + d2 B2
    agg64_kernel<0><<<AGB, 256, 0, stream>>>(
        u3, u2, csr, start, deg, w1, nullptr, nullptr, d2, nullptr, n);
    agg64_kernel<1><<<AGB, 256, 0, stream>>>(
        w1, u1, csr, start, deg, w2, nullptr, nullptr, nullptr, nullptr, n);
    agg64_kernel<2><<<AGB, 256, 0, stream>>>(
        w2, u0, csr, start, deg, nullptr, (float*)d_out, Bv, nullptr, d2, n);
}

// Round 8
// 313.201 us; speedup vs baseline: 1.1134x; 1.1134x over previous
//
#include <hip/hip_runtime.h>

// ---------------------------------------------------------------------------
// GraphConv x3 + FC on MI355X — R14: gemm_u XCD-sibling swizzle + no spills.
// Identity: (A x0)K1 + (A^2 x0)K2 + (A^3 x0)K3 = A(u1 + A(u2 + A u3)),
// u_m = x0 K_m (N x 64). 64-dim propagation (128B gather rows).
// R14: R13's matid-per-block LDS scheme had two measured bugs:
//  (a) siblings (same rows, matid 0..3) were consecutive blockIdx -> spread
//      across 4 XCDs -> x refetched per XCD (FETCH 137.9MB vs 51.2MB x).
//      Fix: xcd=bid&7, matid=(bid>>3)&3, blk=(bid>>5)*8+xcd -> siblings
//      share bid&7 (XCD round-robin heuristic) -> x fetched once.
//  (b) launch_bounds(256,6) -> ~85-reg cap -> VGPR=40 + scratch spills
//      (WRITE 125MB vs 50MB U). Fix: (256,4) -> ~128 regs, a+acc+bq fit.
// ---------------------------------------------------------------------------

typedef short bf16x8 __attribute__((ext_vector_type(8)));
typedef float f32x4 __attribute__((ext_vector_type(4)));

#define CAPB 8192   // bucket capacity (mean 4082, sigma ~64 -> 64 sigma slack)

__device__ inline float bf2f(unsigned short u) {
    union { unsigned int i; float f; } v; v.i = ((unsigned int)u) << 16; return v.f;
}
__device__ inline unsigned short f2bf(float f) {
    union { float f; unsigned int i; } v; v.f = f;
    unsigned int r = v.i + 0x7FFFu + ((v.i >> 16) & 1u);   // RNE
    return (unsigned short)(r >> 16);
}

// ---- prep: stage1 mats [0,64) | edge partition [64,64+NA) ------------------
__global__ __launch_bounds__(512) void prep_kernel(
    const float* __restrict__ Wr2, const float* __restrict__ Wo2,
    const float* __restrict__ fcw, float* __restrict__ K0_2, float* __restrict__ K1_2,
    const int* __restrict__ src, const int* __restrict__ dst,
    int* __restrict__ gcur, unsigned int* __restrict__ bucketed, int e, int NA, int NB) {
    int b = blockIdx.x, t = threadIdx.x;
    if (b < 64) {
        if (t < 256) {
            int matid = b >> 5;
            const float* W = matid ? Wr2 : Wo2;
            float* K = matid ? K1_2 : K0_2;
            int i = t & 127;
            int j = (b & 31) * 2 + (t >> 7);
            float acc = 0.f;
            for (int k = 0; k < 128; k++) acc += W[k * 128 + i] * fcw[j * 128 + k];
            K[i * 64 + j] = acc;
        }
        return;
    }
    b -= 64;
    if (b < NA) {
        __shared__ int sHist[512], sScan[512], sExcl[512], sGbase[512];
        __shared__ unsigned int lbuf[2048];
        __shared__ unsigned short lbkt[2048];
        int e0 = b * 2048;
        int cnt = e - e0; if (cnt > 2048) cnt = 2048;
        sHist[t] = 0;
        __syncthreads();
        unsigned int pk[4]; int bk[4];
#pragma unroll
        for (int k = 0; k < 4; k++) {
            int j = t + k * 512;
            if (j < cnt) {
                int d = dst[e0 + j], s = src[e0 + j];
                bk[k] = d >> 8;
                pk[k] = ((unsigned int)s << 8) | (unsigned int)(d & 255);
                atomicAdd(&sHist[bk[k]], 1);
            } else bk[k] = -1;
        }
        __syncthreads();
        int h = sHist[t];
        if (t < NB && h > 0) sGbase[t] = atomicAdd(&gcur[t], h);
        else sGbase[t] = 0;
        int xv = h; sScan[t] = xv; __syncthreads();
        for (int o = 1; o < 512; o <<= 1) {
            int y = (t >= o) ? sScan[t - o] : 0;
            __syncthreads();
            xv += y; sScan[t] = xv;
            __syncthreads();
        }
        sExcl[t] = xv - h;      // block-local exclusive offsets per bucket
        sHist[t] = 0;           // becomes local cursor
        __syncthreads();
#pragma unroll
        for (int k = 0; k < 4; k++) {
            if (bk[k] >= 0) {
                int r = atomicAdd(&sHist[bk[k]], 1);
                int pos = sExcl[bk[k]] + r;
                lbuf[pos] = pk[k];
                lbkt[pos] = (unsigned short)bk[k];
            }
        }
        __syncthreads();
        for (int j = t; j < cnt; j += 512) {
            int b2 = lbkt[j];
            int idx = sGbase[b2] + (j - sExcl[b2]);
            if (idx < CAPB) bucketed[(size_t)b2 * CAPB + idx] = lbuf[j];
        }
    }
}

// ---- pass B: per-bucket deg/start/csr --------------------------------------
__global__ __launch_bounds__(256) void partB_kernel(
    const unsigned int* __restrict__ bucketed, const int* __restrict__ gcur,
    int* __restrict__ deg, int* __restrict__ start, int* __restrict__ csr, int n) {
    int b = blockIdx.x, t = threadIdx.x;
    __shared__ int ldeg[256], lscan[256], red[256];
    __shared__ int csr_base_s;
    int cnt = gcur[b]; if (cnt > CAPB) cnt = CAPB;
    // csr base = sum of counts of buckets < b
    int part = 0;
    for (int q = t; q < b; q += 256) { int c = gcur[q]; part += (c > CAPB ? CAPB : c); }
    red[t] = part; __syncthreads();
    for (int o = 128; o > 0; o >>= 1) { if (t < o) red[t] += red[t + o]; __syncthreads(); }
    if (t == 0) csr_base_s = red[0];
    ldeg[t] = 0;
    __syncthreads();
    const unsigned int* bd = bucketed + (size_t)b * CAPB;
    for (int j = t; j < cnt; j += 256) atomicAdd(&ldeg[bd[j] & 255], 1);
    __syncthreads();
    int h = ldeg[t];
    int xv = h; lscan[t] = xv; __syncthreads();
    for (int o = 1; o < 256; o <<= 1) {
        int y = (t >= o) ? lscan[t - o] : 0;
        __syncthreads();
        xv += y; lscan[t] = xv;
        __syncthreads();
    }
    int excl = xv - h;
    int csr_base = csr_base_s;
    int node = b * 256 + t;
    if (node < n) { deg[node] = h; start[node] = csr_base + excl; }
    __syncthreads();
    lscan[t] = excl;    // per-local-node exclusive offset
    ldeg[t] = 0;        // cursor
    __syncthreads();
    for (int j = t; j < cnt; j += 256) {
        unsigned int pkd = bd[j];
        int d = pkd & 255;
        int r = atomicAdd(&ldeg[d], 1);
        csr[csr_base + lscan[d] + r] = (int)(pkd >> 8);
    }
}

// ---- stage2: K*_1 from layer-1 (0-based) weights ---------------------------
__global__ __launch_bounds__(256) void stage2_kernel(
    const float* __restrict__ Wr1, const float* __restrict__ Wo1,
    const float* __restrict__ K0_2, const float* __restrict__ K1_2,
    float* __restrict__ K0_1, float* __restrict__ K1_1, float* __restrict__ K2_1) {
    int b = blockIdx.x, t = threadIdx.x;
    int matid = b >> 5;
    int i = t & 127;
    int j = (b & 31) * 2 + (t >> 7);
    float acc = 0.f;
    if (matid == 0) {
        for (int k = 0; k < 128; k++) acc += Wo1[k * 128 + i] * K0_2[k * 64 + j];
        K0_1[i * 64 + j] = acc;
    } else if (matid == 1) {
        for (int k = 0; k < 128; k++)
            acc += Wr1[k * 128 + i] * K0_2[k * 64 + j] + Wo1[k * 128 + i] * K1_2[k * 64 + j];
        K1_1[i * 64 + j] = acc;
    } else {
        for (int k = 0; k < 128; k++) acc += Wr1[k * 128 + i] * K1_2[k * 64 + j];
        K2_1[i * 64 + j] = acc;
    }
}

// ---- stage3: final K0..K3 packed bf16 (permuted slots) + bias vectors ------
// Nw slot p = ((c&3)<<4)|(c>>2) holds logical output column c, so gemm_u's
// tile t / lane m (reading slot t*16+m) emits logical column 4m+t.
__global__ __launch_bounds__(256) void stage3_kernel(
    const float* __restrict__ Wr0, const float* __restrict__ Wo0,
    const float* __restrict__ K0_1, const float* __restrict__ K1_1, const float* __restrict__ K2_1,
    const float* __restrict__ K0_2, const float* __restrict__ K1_2,
    const float* __restrict__ br, const float* __restrict__ fcw, const float* __restrict__ fcb,
    unsigned short* __restrict__ Nw, float* __restrict__ Bv) {
    int b = blockIdx.x, t = threadIdx.x;
    if (b < 128) {
        int matid = b >> 5;
        int i = t & 127;
        int o = (b & 31) * 2 + (t >> 7);
        float acc = 0.f;
        if (matid == 0) {
            for (int k = 0; k < 128; k++) acc += Wo0[k * 128 + i] * K0_1[k * 64 + o];
        } else if (matid == 1) {
            for (int k = 0; k < 128; k++)
                acc += Wr0[k * 128 + i] * K0_1[k * 64 + o] + Wo0[k * 128 + i] * K1_1[k * 64 + o];
        } else if (matid == 2) {
            for (int k = 0; k < 128; k++)
                acc += Wr0[k * 128 + i] * K1_1[k * 64 + o] + Wo0[k * 128 + i] * K2_1[k * 64 + o];
        } else {
            for (int k = 0; k < 128; k++) acc += Wr0[k * 128 + i] * K2_1[k * 64 + o];
        }
        int p = ((o & 3) << 4) | (o >> 2);
        Nw[p * 512 + matid * 128 + i] = f2bf(acc);
        return;
    }
    const float* br0 = br;
    const float* br1 = br + 128;
    const float* br2 = br + 256;
    int j = t & 63;
    int which = t >> 6;
    if (which == 0) {
        float acc = fcb[j];
        for (int k = 0; k < 128; k++) acc += br2[k] * fcw[j * 128 + k];
        for (int k = 0; k < 128; k++) acc += br1[k] * K0_2[k * 64 + j];
        for (int k = 0; k < 128; k++) acc += br0[k] * K0_1[k * 64 + j];
        Bv[j] = acc;                       // B0
    } else if (which == 1) {
        float acc = 0.f;
        for (int k = 0; k < 128; k++) acc += br1[k] * K1_2[k * 64 + j];
        for (int k = 0; k < 128; k++) acc += br0[k] * K1_1[k * 64 + j];
        Bv[64 + j] = acc;                  // B1
    } else if (which == 2) {
        float acc = 0.f;
        for (int k = 0; k < 128; k++) acc += br0[k] * K2_1[k * 64 + j];
        Bv[128 + j] = acc;                 // B2
    }
}

// ---- gemm_u: U[m][n][64] = bf16(x0 @ K_m), m=0..3, MFMA ---------------------
// Sibling swizzle: xcd=bid&7, matid=(bid>>3)&3, blk=(bid>>5)*8+xcd so the 4
// blocks sharing x rows land on the same XCD (bid%8 round-robin heuristic).
// Block stages its 16 KB B-panel to LDS once; 4 waves x 2 row-tiles each.
__global__ __launch_bounds__(256, 4) void gemm_u_kernel(
    const float* __restrict__ x, const unsigned short* __restrict__ Nw,
    unsigned short* __restrict__ U, int n, int NGB) {
    __shared__ unsigned short Blds[8192];   // 16 KB
    int bid   = blockIdx.x;
    int matid = (bid >> 3) & 3;
    int blk   = (bid >> 5) * 8 + (bid & 7);
    if (blk >= NGB) return;                 // uniform per block (before syncthreads)
    int tid   = threadIdx.x;

    // stage B[matid]: 1024 x 16B groups, contiguous LDS writes
    {
        const uint4* nw4 = (const uint4*)Nw;   // Nw: 64 slots x 512 elems = 64 x 64 uint4
        uint4* lds4 = (uint4*)Blds;
        for (int g = tid; g < 1024; g += 256) {
            int slot = g & 63;
            int kq   = g >> 6;                 // kk*4+quad
            lds4[g] = nw4[(size_t)slot * 64 + matid * 16 + kq];
        }
    }
    __syncthreads();

    int wave = tid >> 6;
    int lane = tid & 63;
    int m    = lane & 15;
    int quad = lane >> 4;
    size_t n64 = (size_t)n * 64;
    unsigned short* up = U + (size_t)matid * n64;

#pragma unroll
    for (int w = 0; w < 2; w++) {
        int row0 = (blk * 8 + wave * 2 + w) * 16;
        if (row0 >= n) break;

        // load + convert this tile's x rows (row-clamped)
        int arow = row0 + m; if (arow >= n) arow = n - 1;
        const float* xr = x + (size_t)arow * 128 + quad * 8;
        bf16x8 a[4];
#pragma unroll
        for (int kk = 0; kk < 4; kk++) {
            float4 v0 = *(const float4*)(xr + kk * 32);
            float4 v1 = *(const float4*)(xr + kk * 32 + 4);
            a[kk][0] = (short)f2bf(v0.x); a[kk][1] = (short)f2bf(v0.y);
            a[kk][2] = (short)f2bf(v0.z); a[kk][3] = (short)f2bf(v0.w);
            a[kk][4] = (short)f2bf(v1.x); a[kk][5] = (short)f2bf(v1.y);
            a[kk][6] = (short)f2bf(v1.z); a[kk][7] = (short)f2bf(v1.w);
        }

        f32x4 acc[4];
#pragma unroll
        for (int t = 0; t < 4; t++) acc[t] = (f32x4){0.f, 0.f, 0.f, 0.f};
#pragma unroll
        for (int kk = 0; kk < 4; kk++) {
            bf16x8 bq[4];
#pragma unroll
            for (int t = 0; t < 4; t++)
                bq[t] = *(const bf16x8*)(Blds + ((kk * 4 + quad) * 64 + t * 16 + m) * 8);
#pragma unroll
            for (int t = 0; t < 4; t++)
                acc[t] = __builtin_amdgcn_mfma_f32_16x16x32_bf16(a[kk], bq[t], acc[t], 0, 0, 0);
        }

#pragma unroll
        for (int r = 0; r < 4; r++) {
            int orow = row0 + quad * 4 + r;
            if (orow < n) {
                ushort4 o4;
                o4.x = f2bf(acc[0][r]); o4.y = f2bf(acc[1][r]);
                o4.z = f2bf(acc[2][r]); o4.w = f2bf(acc[3][r]);
                *(ushort4*)(up + (size_t)orow * 64 + m * 4) = o4;
            }
        }
    }
}

// ---- agg64: 8 nodes per wave, one 8-lane group per node, shuffle-free ------
// MODE 0: outb = A*in + addv, d2 = A*deg fused
// MODE 1: outb = A*in + addv
// MODE 2: outf = A*in + addv + B0 + deg*B1 + d2*B2   (final f32 output)
template <int MODE>
__global__ __launch_bounds__(256) void agg64_kernel(
    const unsigned short* __restrict__ in, const unsigned short* __restrict__ addv,
    const int* __restrict__ csr, const int* __restrict__ start, const int* __restrict__ deg,
    unsigned short* __restrict__ outb, float* __restrict__ outf,
    const float* __restrict__ Bv, int* __restrict__ d2w, const int* __restrict__ d2r, int n) {
    int tid = threadIdx.x;
    int fl  = tid & 7;                       // lane within 8-lane group
    int node = blockIdx.x * 32 + (tid >> 3); // one node per group
    if (node >= n) return;

    // hoist bias columns (node-independent) for MODE 2
    float b0[8], b1[8], b2[8];
    if (MODE == 2) {
#pragma unroll
        for (int j = 0; j < 8; j++) {
            int o = fl * 8 + j;
            b0[j] = Bv[o]; b1[j] = Bv[64 + o]; b2[j] = Bv[128 + o];
        }
    }

    int s0 = start[node];
    int d  = deg[node];

    float acc[8];
#pragma unroll
    for (int j = 0; j < 8; j++) acc[j] = 0.f;
    int dsum = 0;

#pragma unroll 4
    for (int i = 0; i < d; i++) {
        int s = csr[s0 + i];
        bf16x8 v = *(const bf16x8*)(in + (size_t)s * 64 + fl * 8);
#pragma unroll
        for (int j = 0; j < 8; j++) acc[j] += bf2f((unsigned short)v[j]);
        if (MODE == 0 && fl == 0) dsum += deg[s];
    }
    if (MODE == 0 && fl == 0) d2w[node] = dsum;

    bf16x8 av = *(const bf16x8*)(addv + (size_t)node * 64 + fl * 8);
    if (MODE < 2) {
        bf16x8 o;
#pragma unroll
        for (int j = 0; j < 8; j++) o[j] = (short)f2bf(acc[j] + bf2f((unsigned short)av[j]));
        *(bf16x8*)(outb + (size_t)node * 64 + fl * 8) = o;
    } else {
        float dg = (float)d;
        float dd = (float)d2r[node];
        float ov[8];
#pragma unroll
        for (int j = 0; j < 8; j++)
            ov[j] = acc[j] + bf2f((unsigned short)av[j]) + b0[j] + dg * b1[j] + dd * b2[j];
        float* op = outf + (size_t)node * 64 + fl * 8;
        *(float4*)(op)     = make_float4(ov[0], ov[1], ov[2], ov[3]);
        *(float4*)(op + 4) = make_float4(ov[4], ov[5], ov[6], ov[7]);
    }
}

// ---------------------------------------------------------------------------
extern "C" void kernel_launch(void* const* d_in, const int* in_sizes, int n_in,
                              void* d_out, int out_size, void* d_ws, size_t ws_size,
                              hipStream_t stream) {
    const float* x      = (const float*)d_in[0];
    const int*   ei     = (const int*)d_in[1];
    const float* W_rel  = (const float*)d_in[2];
    const float* b_rel  = (const float*)d_in[3];
    const float* W_root = (const float*)d_in[4];
    const float* fc_w   = (const float*)d_in[5];
    const float* fc_b   = (const float*)d_in[6];

    const int n = in_sizes[0] / 128;      // 100000
    const int e = in_sizes[1] / 2;        // 1600000
    const int* src = ei;
    const int* dst = ei + e;

    const int NB  = (n + 255) >> 8;       // 391 buckets of 256 nodes
    const int NA  = (e + 2047) / 2048;    // 782 partition blocks
    const int NT  = (n + 15) / 16;        // MFMA row-tiles
    const int NGB = (NT + 7) / 8;         // row-blocks (8 tiles each) = 782
    const int NGBp = (NGB + 7) & ~7;      // pad to multiple of 8 for swizzle

    char* p = (char*)d_ws;
    auto take = [&](size_t bytes) -> void* {
        void* r = (void*)p;
        p += (bytes + 255) & ~(size_t)255;
        return r;
    };
    unsigned short* U  = (unsigned short*)take((size_t)n * 256 * 2);  // u0..u3
    unsigned short* w1 = (unsigned short*)take((size_t)n * 64 * 2);
    unsigned short* w2 = (unsigned short*)take((size_t)n * 64 * 2);
    int* deg    = (int*)take((size_t)n * 4);
    int* start  = (int*)take((size_t)n * 4);
    int* d2     = (int*)take((size_t)n * 4);
    int* csr    = (int*)take((size_t)e * 4);
    unsigned int* bucketed = (unsigned int*)take((size_t)NB * CAPB * 4);
    int* gcur   = (int*)take((size_t)NB * 4);
    float* K0_2 = (float*)take(128 * 64 * 4);
    float* K1_2 = (float*)take(128 * 64 * 4);
    float* K0_1 = (float*)take(128 * 64 * 4);
    float* K1_1 = (float*)take(128 * 64 * 4);
    float* K2_1 = (float*)take(128 * 64 * 4);
    unsigned short* Nw = (unsigned short*)take(64 * 512 * 2);
    float* Bv   = (float*)take(192 * 4);

    size_t n64 = (size_t)n * 64;
    unsigned short* u0 = U;
    unsigned short* u1 = U + n64;
    unsigned short* u2 = U + 2 * n64;
    unsigned short* u3 = U + 3 * n64;

    hipMemsetAsync(gcur, 0, (size_t)NB * 4, stream);
    prep_kernel<<<64 + NA, 512, 0, stream>>>(
        W_rel + 2 * 16384, W_root + 2 * 16384, fc_w, K0_2, K1_2,
        src, dst, gcur, bucketed, e, NA, NB);
    partB_kernel<<<NB, 256, 0, stream>>>(bucketed, gcur, deg, start, csr, n);
    stage2_kernel<<<96, 256, 0, stream>>>(
        W_rel + 16384, W_root + 16384, K0_2, K1_2, K0_1, K1_1, K2_1);
    stage3_kernel<<<129, 256, 0, stream>>>(
        W_rel, W_root, K0_1, K1_1, K2_1, K0_2, K1_2, b_rel, fc_w, fc_b, Nw, Bv);

    gemm_u_kernel<<<NGBp * 4, 256, 0, stream>>>(x, Nw, U, n, NGB);

    const int AGB = (n + 31) / 32;        // 32 nodes per 256-thread block
    // w1 = A u3 + u2 ; w2 = A w1 + u1 ; out = A w2 + u0 + B0 + deg B1 + d2 B2
    agg64_kernel<0><<<AGB, 256, 0, stream>>>(
        u3, u2, csr, start, deg, w1, nullptr, nullptr, d2, nullptr, n);
    agg64_kernel<1><<<AGB, 256, 0, stream>>>(
        w1, u1, csr, start, deg, w2, nullptr, nullptr, nullptr, nullptr, n);
    agg64_kernel<2><<<AGB, 256, 0, stream>>>(
        w2, u0, csr, start, deg, nullptr, (float*)d_out, Bv, nullptr, d2, n);
}